// Round 1
// baseline (49.316 us; speedup 1.0000x reference)
//
#include <hip/hip_runtime.h>

#define DD 256
#define SS 128
#define BB 16
#define TOK 8
#define NSC (SS/TOK)   // 16

// ws layout (floats):
//  LT   [B][D][S]          524288
//  RT   [B][D][S]          524288
//  sumLp[B][NSC][D]         65536
//  sumRp[B][NSC][D]         65536
//  absP [B][4][4][64]       16384
// total 1,196,032 floats = ~4.8 MB

__global__ __launch_bounds__(256) void k_proj(
    const int* __restrict__ X, const float* __restrict__ emb,
    const float* __restrict__ Wl, const float* __restrict__ bl,
    const float* __restrict__ Wr, const float* __restrict__ br,
    float* __restrict__ LT, float* __restrict__ RT,
    float* __restrict__ sumLp, float* __restrict__ sumRp)
{
    __shared__ float e_lds[TOK * DD];
    const int tid = threadIdx.x;
    const int bx  = blockIdx.x;
    const int b   = bx >> 4;
    const int sc  = bx & 15;
    const int s0  = sc * TOK;

    // stage 8 embedding rows (2048 f32 = 512 float4)
    for (int v = tid; v < TOK * DD / 4; v += 256) {
        int t  = v >> 6;          // 64 float4 per row
        int c4 = v & 63;
        int tok = X[b * SS + s0 + t];
        *(float4*)&e_lds[t * DD + c4 * 4] =
            *(const float4*)&emb[(size_t)tok * DD + c4 * 4];
    }
    __syncthreads();

    const int d = tid;
    float accl[TOK], accr[TOK];
    const float blv = bl[d], brv = br[d];
#pragma unroll
    for (int t = 0; t < TOK; ++t) { accl[t] = blv; accr[t] = brv; }

    const float4* wl4 = (const float4*)(Wl + (size_t)d * DD);
    const float4* wr4 = (const float4*)(Wr + (size_t)d * DD);
    for (int k4 = 0; k4 < DD / 4; ++k4) {
        float4 wl = wl4[k4];
        float4 wr = wr4[k4];
#pragma unroll
        for (int t = 0; t < TOK; ++t) {
            float4 e4 = *(float4*)&e_lds[t * DD + k4 * 4];
            accl[t] = fmaf(e4.x, wl.x, accl[t]);
            accl[t] = fmaf(e4.y, wl.y, accl[t]);
            accl[t] = fmaf(e4.z, wl.z, accl[t]);
            accl[t] = fmaf(e4.w, wl.w, accl[t]);
            accr[t] = fmaf(e4.x, wr.x, accr[t]);
            accr[t] = fmaf(e4.y, wr.y, accr[t]);
            accr[t] = fmaf(e4.z, wr.z, accr[t]);
            accr[t] = fmaf(e4.w, wr.w, accr[t]);
        }
    }

    // transposed stores: LT[b][d][s0..s0+7] contiguous
    float* ltp = LT + ((size_t)(b * DD + d)) * SS + s0;
    float* rtp = RT + ((size_t)(b * DD + d)) * SS + s0;
    *(float4*)&ltp[0] = make_float4(accl[0], accl[1], accl[2], accl[3]);
    *(float4*)&ltp[4] = make_float4(accl[4], accl[5], accl[6], accl[7]);
    *(float4*)&rtp[0] = make_float4(accr[0], accr[1], accr[2], accr[3]);
    *(float4*)&rtp[4] = make_float4(accr[4], accr[5], accr[6], accr[7]);

    float sl = 0.f, sr = 0.f;
#pragma unroll
    for (int t = 0; t < TOK; ++t) { sl += accl[t]; sr += accr[t]; }
    sumLp[(b * NSC + sc) * DD + d] = sl;
    sumRp[(b * NSC + sc) * DD + d] = sr;
}

// block = (b, dchunk of 64 d's, isplit of 32 i's); 256 threads = 64 d x 4 j-groups
__global__ __launch_bounds__(256) void k_pairs(
    const float* __restrict__ LT, const float* __restrict__ RT,
    float* __restrict__ absP)
{
    __shared__ float Ll[64 * 33];    // [d][i] pad->stride 33: bank=(d+i)%32, 2-way free
    __shared__ float Rl[64 * 129];   // [d][j] stride 129
    __shared__ float red[256];
    const int tid = threadIdx.x;
    const int bx  = blockIdx.x;
    const int b   = bx >> 4;
    const int dc  = (bx >> 2) & 3;
    const int is  = bx & 3;

    const float* Lg = LT + ((size_t)(b * DD + dc * 64)) * SS;
    const float* Rg = RT + ((size_t)(b * DD + dc * 64)) * SS;

    // L chunk: 64 rows x 32 cols (i-range) = 512 float4
    for (int v = tid; v < 64 * 8; v += 256) {
        int r = v >> 3, c4 = v & 7;
        float4 x = *(const float4*)&Lg[r * SS + is * 32 + c4 * 4];
        float* p = &Ll[r * 33 + c4 * 4];
        p[0] = x.x; p[1] = x.y; p[2] = x.z; p[3] = x.w;
    }
    // R chunk: 64 rows x 128 cols = 2048 float4
    for (int v = tid; v < 64 * 32; v += 256) {
        int r = v >> 5, c4 = v & 31;
        float4 x = *(const float4*)&Rg[r * SS + c4 * 4];
        float* p = &Rl[r * 129 + c4 * 4];
        p[0] = x.x; p[1] = x.y; p[2] = x.z; p[3] = x.w;
    }
    __syncthreads();

    const int dl = tid & 63;
    const int jg = tid >> 6;
    float rr[32];
#pragma unroll
    for (int j = 0; j < 32; ++j) rr[j] = Rl[dl * 129 + jg * 32 + j];

    float a0 = 0.f, a1 = 0.f, a2 = 0.f, a3 = 0.f;
    for (int i = 0; i < 32; ++i) {
        float l = Ll[dl * 33 + i];
#pragma unroll
        for (int j = 0; j < 32; j += 4) {
            a0 += fabsf(l + rr[j + 0]);
            a1 += fabsf(l + rr[j + 1]);
            a2 += fabsf(l + rr[j + 2]);
            a3 += fabsf(l + rr[j + 3]);
        }
    }
    red[tid] = (a0 + a1) + (a2 + a3);
    __syncthreads();
    if (tid < 64) {
        float s = red[tid] + red[tid + 64] + red[tid + 128] + red[tid + 192];
        absP[((b * 4 + dc) * 4 + is) * 64 + tid] = s;
    }
}

__global__ __launch_bounds__(256) void k_final(
    const float* __restrict__ sumLp, const float* __restrict__ sumRp,
    const float* __restrict__ absP,
    const float* __restrict__ Wrel, const float* __restrict__ brel,
    float* __restrict__ out)
{
    __shared__ float plds[DD];
    const int tid = threadIdx.x;
    const int b   = blockIdx.x;

    float sl = 0.f, sr = 0.f;
#pragma unroll
    for (int sc = 0; sc < NSC; ++sc) {
        sl += sumLp[(b * NSC + sc) * DD + tid];
        sr += sumRp[(b * NSC + sc) * DD + tid];
    }
    const int dc = tid >> 6, dl = tid & 63;
    float sa = 0.f;
#pragma unroll
    for (int is = 0; is < 4; ++is)
        sa += absP[((b * 4 + dc) * 4 + is) * 64 + dl];

    // pooled = (S*(sumL+sumR) + sumAbs) / (2*S*S)
    plds[tid] = (128.0f * (sl + sr) + sa) * (1.0f / 32768.0f);
    __syncthreads();

    float acc = brel[tid];
    const float4* w4 = (const float4*)(Wrel + (size_t)tid * DD);
    for (int k4 = 0; k4 < DD / 4; ++k4) {
        float4 p = *(float4*)&plds[k4 * 4];
        float4 w = w4[k4];
        acc = fmaf(p.x, w.x, acc);
        acc = fmaf(p.y, w.y, acc);
        acc = fmaf(p.z, w.z, acc);
        acc = fmaf(p.w, w.w, acc);
    }
    out[b * DD + tid] = acc;
}

extern "C" void kernel_launch(void* const* d_in, const int* in_sizes, int n_in,
                              void* d_out, int out_size, void* d_ws, size_t ws_size,
                              hipStream_t stream) {
    const int*   X    = (const int*)d_in[0];
    const float* emb  = (const float*)d_in[1];
    const float* Wl   = (const float*)d_in[2];
    const float* bl   = (const float*)d_in[3];
    const float* Wr   = (const float*)d_in[4];
    const float* br   = (const float*)d_in[5];
    const float* Wrel = (const float*)d_in[6];
    const float* brel = (const float*)d_in[7];
    float* out = (float*)d_out;

    float* ws = (float*)d_ws;
    float* LT    = ws;                       // 524288
    float* RT    = LT + (size_t)BB * DD * SS; // 524288
    float* sumLp = RT + (size_t)BB * DD * SS; // 65536
    float* sumRp = sumLp + BB * NSC * DD;     // 65536
    float* absP  = sumRp + BB * NSC * DD;     // 16384

    k_proj<<<BB * NSC, 256, 0, stream>>>(X, emb, Wl, bl, Wr, br,
                                         LT, RT, sumLp, sumRp);
    k_pairs<<<BB * 4 * 4, 256, 0, stream>>>(LT, RT, absP);
    k_final<<<BB, 256, 0, stream>>>(sumLp, sumRp, absP, Wrel, brel, out);
}